// Round 1
// baseline (2809.248 us; speedup 1.0000x reference)
//
#include <hip/hip_runtime.h>
#include <math.h>

#define B_  2
#define N_  2048
#define D_  1024
#define H_  16
#define HD_ 64

// ---------------------------------------------------------------------------
// GEMM: C = A @ W^T (+ bias).  A: [M x 1024] row-major, W: [1024 x 1024]
// row-major (torch Linear weight), so C[r][c] = dot(A[r,:], W[c,:]).
// MODE 0: scatter C to [B, H, N, HD] layout (for Q/K/V), no bias.
// MODE 1: plain [M x 1024] row-major + bias (final projection).
// 64x64 output tile per 256-thread block, 4x4 micro-tile per thread,
// LDS k-chunks of 16 with +1 padding (stride 17) to avoid bank conflicts.
// ---------------------------------------------------------------------------
template <int MODE>
__global__ __launch_bounds__(256)
void gemm_xwT(const float* __restrict__ A, const float* __restrict__ W,
              const float* __restrict__ bias, float* __restrict__ C)
{
    __shared__ float As[64][17];
    __shared__ float Bs[64][17];
    const int t  = threadIdx.x;
    const int tx = t & 15;
    const int ty = t >> 4;
    const int tileM = blockIdx.x * 64;
    const int tileN = blockIdx.y * 64;

    float acc[4][4];
#pragma unroll
    for (int i = 0; i < 4; ++i)
#pragma unroll
        for (int j = 0; j < 4; ++j) acc[i][j] = 0.f;

    for (int k0 = 0; k0 < D_; k0 += 16) {
#pragma unroll
        for (int l = 0; l < 4; ++l) {
            int idx = l * 256 + t;
            int r = idx >> 4, kk = idx & 15;
            As[r][kk] = A[(size_t)(tileM + r) * D_ + k0 + kk];
            Bs[r][kk] = W[(size_t)(tileN + r) * D_ + k0 + kk];
        }
        __syncthreads();
#pragma unroll
        for (int kk = 0; kk < 16; ++kk) {
            float a[4], b[4];
#pragma unroll
            for (int i = 0; i < 4; ++i) a[i] = As[ty * 4 + i][kk];
#pragma unroll
            for (int j = 0; j < 4; ++j) b[j] = Bs[tx * 4 + j][kk];
#pragma unroll
            for (int i = 0; i < 4; ++i)
#pragma unroll
                for (int j = 0; j < 4; ++j) acc[i][j] += a[i] * b[j];
        }
        __syncthreads();
    }

#pragma unroll
    for (int i = 0; i < 4; ++i) {
        int row = tileM + ty * 4 + i;
#pragma unroll
        for (int j = 0; j < 4; ++j) {
            int col = tileN + tx * 4 + j;
            if (MODE == 0) {
                int b = row / N_, n = row % N_;
                int h = col / HD_, d = col % HD_;
                C[(((size_t)(b * H_ + h)) * N_ + n) * HD_ + d] = acc[i][j];
            } else {
                C[(size_t)row * D_ + col] = acc[i][j] + bias[col];
            }
        }
    }
}

// ---------------------------------------------------------------------------
// Adaptive-temperature causal flash attention (fp32).
// Grid: (qb 0..63, bh 0..31). Block: 256 threads.
// Q/K/V: [B*H, N, HD].  O written as [B, N, D] (b, n, h*64+d) row-major.
//
// Pass 1 (online over key blocks): per query row track
//   m = max(l), Z = sum e^(l-m), S = sum e^(l-m)*(l-m)
//   => entropy H = log Z - S/Z  => beta via poly.
// Pass 2: recompute logits, w = e^(beta*(l-m)), accumulate Z' = sum w and
//   O = sum w*V, then O /= Z'.  (max of beta*l is beta*m since beta>=1.)
// LDS strides padded (65 / 33) so stride-64 row accesses don't all hit bank 0.
// ---------------------------------------------------------------------------
__global__ __launch_bounds__(256)
void attn_adaptive(const float* __restrict__ Q, const float* __restrict__ K,
                   const float* __restrict__ V, float* __restrict__ O)
{
    const int qb = blockIdx.x;   // query block: rows qb*32 .. +31
    const int bh = blockIdx.y;   // b*H + h
    const size_t base = (size_t)bh * N_ * HD_;

    __shared__ float Qs[32][65];
    __shared__ float Ks[32][65];
    __shared__ float Vs[32][65];
    __shared__ float Ss[32][33];
    __shared__ float rowM[32], rowZ[32], rowS[32], rowB[32], rowZp[32];

    const int t  = threadIdx.x;
    const int r  = t >> 3;        // row within tile, 0..31
    const int c0 = (t & 7) * 4;   // S-tile col group (4 cols)
    const int cp = (t & 7) * 8;   // O col group (8 cols)
    const float scale = 0.125f;   // 1/sqrt(64)
    const float NEGBIG = -1e30f;

#pragma unroll
    for (int l = 0; l < 8; ++l) {
        int idx = l * 256 + t;
        Qs[idx >> 6][idx & 63] = Q[base + (size_t)(qb * 32) * HD_ + idx];
    }
    if (t < 32) { rowM[t] = -3.0e38f; rowZ[t] = 0.f; rowS[t] = 0.f; }

    // ---------------- pass 1: m, Z, S ----------------
    for (int kb = 0; kb <= qb; ++kb) {
        __syncthreads();   // prev iter's Ss readers done before reload
#pragma unroll
        for (int l = 0; l < 8; ++l) {
            int idx = l * 256 + t;
            Ks[idx >> 6][idx & 63] = K[base + (size_t)(kb * 32) * HD_ + idx];
        }
        __syncthreads();

        float s0 = 0.f, s1 = 0.f, s2 = 0.f, s3 = 0.f;
        for (int k = 0; k < 64; ++k) {
            float qv = Qs[r][k];
            s0 += qv * Ks[c0 + 0][k];
            s1 += qv * Ks[c0 + 1][k];
            s2 += qv * Ks[c0 + 2][k];
            s3 += qv * Ks[c0 + 3][k];
        }
        const int gi = qb * 32 + r;
        const int gj = kb * 32 + c0;
        Ss[r][c0 + 0] = (gj + 0 <= gi) ? s0 * scale : NEGBIG;
        Ss[r][c0 + 1] = (gj + 1 <= gi) ? s1 * scale : NEGBIG;
        Ss[r][c0 + 2] = (gj + 2 <= gi) ? s2 * scale : NEGBIG;
        Ss[r][c0 + 3] = (gj + 3 <= gi) ? s3 * scale : NEGBIG;
        __syncthreads();

        if (t < 32) {
            float m = rowM[t], Z = rowZ[t], S = rowS[t];
            float bm = m;
            for (int j = 0; j < 32; ++j) bm = fmaxf(bm, Ss[t][j]);
            float corr = __expf(m - bm);          // 0 on first block (m=-3e38)
            S = corr * (S + (m - bm) * Z);
            Z = corr * Z;
            for (int j = 0; j < 32; ++j) {
                float lv = Ss[t][j];              // NEGBIG -> e=0, e*(lv-bm)=0
                float e = __expf(lv - bm);
                Z += e;
                S += e * (lv - bm);
            }
            rowM[t] = bm; rowZ[t] = Z; rowS[t] = S;
        }
    }
    __syncthreads();

    // ---------------- entropy -> beta ----------------
    if (t < 32) {
        float Z = rowZ[t], S = rowS[t];
        float Hent = __logf(Z) - S / Z;
        float beta = 1.f;
        if (Hent > 0.5f) {
            float e2 = Hent * Hent;
            float p = -0.037f * e2 * e2 + 0.481f * e2 * Hent - 2.3f * e2
                      + 4.917f * Hent - 1.791f;
            beta = fmaxf(p, 1.f);
        }
        rowB[t]  = beta;
        rowZp[t] = 0.f;
    }

    float o[8];
#pragma unroll
    for (int i = 0; i < 8; ++i) o[i] = 0.f;

    // ---------------- pass 2: w = e^(beta*(l-m)), O += w*V, Z' += w ----------
    for (int kb = 0; kb <= qb; ++kb) {
        __syncthreads();   // prev iter's Vs/Ss readers done before reload
#pragma unroll
        for (int l = 0; l < 8; ++l) {
            int idx = l * 256 + t;
            int rr = idx >> 6, cc = idx & 63;
            Ks[rr][cc] = K[base + (size_t)(kb * 32) * HD_ + idx];
            Vs[rr][cc] = V[base + (size_t)(kb * 32) * HD_ + idx];
        }
        __syncthreads();

        float s0 = 0.f, s1 = 0.f, s2 = 0.f, s3 = 0.f;
        for (int k = 0; k < 64; ++k) {
            float qv = Qs[r][k];
            s0 += qv * Ks[c0 + 0][k];
            s1 += qv * Ks[c0 + 1][k];
            s2 += qv * Ks[c0 + 2][k];
            s3 += qv * Ks[c0 + 3][k];
        }
        const int gi = qb * 32 + r;
        const int gj = kb * 32 + c0;
        const float m = rowM[r], beta = rowB[r];
        Ss[r][c0 + 0] = (gj + 0 <= gi) ? __expf(beta * (s0 * scale - m)) : 0.f;
        Ss[r][c0 + 1] = (gj + 1 <= gi) ? __expf(beta * (s1 * scale - m)) : 0.f;
        Ss[r][c0 + 2] = (gj + 2 <= gi) ? __expf(beta * (s2 * scale - m)) : 0.f;
        Ss[r][c0 + 3] = (gj + 3 <= gi) ? __expf(beta * (s3 * scale - m)) : 0.f;
        __syncthreads();

        if (t < 32) {
            float zp = 0.f;
            for (int j = 0; j < 32; ++j) zp += Ss[t][j];
            rowZp[t] += zp;
        }
#pragma unroll 4
        for (int j = 0; j < 32; ++j) {
            float w = Ss[r][j];
#pragma unroll
            for (int i = 0; i < 8; ++i) o[i] += w * Vs[j][cp + i];
        }
    }
    __syncthreads();

    const float invz = 1.f / rowZp[r];
    const int b = bh / H_, h = bh % H_;
    float* outp = O + ((size_t)(b * N_ + qb * 32 + r)) * D_ + h * HD_ + cp;
#pragma unroll
    for (int i = 0; i < 8; ++i) outp[i] = o[i] * invz;
}

// ---------------------------------------------------------------------------
extern "C" void kernel_launch(void* const* d_in, const int* in_sizes, int n_in,
                              void* d_out, int out_size, void* d_ws, size_t ws_size,
                              hipStream_t stream)
{
    const float* x  = (const float*)d_in[0];
    const float* Wq = (const float*)d_in[1];
    const float* Wk = (const float*)d_in[2];
    const float* Wv = (const float*)d_in[3];
    const float* Wo = (const float*)d_in[4];
    const float* bo = (const float*)d_in[5];
    float* out = (float*)d_out;

    const size_t per = (size_t)B_ * H_ * N_ * HD_;   // 4 Mi floats = 16 MB
    float* q  = (float*)d_ws;
    float* k  = q + per;
    float* v  = k + per;
    float* ao = v + per;                              // attention out, [B,N,D]

    dim3 gb(64, 16), blk(256);
    gemm_xwT<0><<<gb, blk, 0, stream>>>(x, Wq, nullptr, q);
    gemm_xwT<0><<<gb, blk, 0, stream>>>(x, Wk, nullptr, k);
    gemm_xwT<0><<<gb, blk, 0, stream>>>(x, Wv, nullptr, v);

    attn_adaptive<<<dim3(64, 32), blk, 0, stream>>>(q, k, v, ao);

    gemm_xwT<1><<<gb, blk, 0, stream>>>(ao, Wo, bo, out);
}

// Round 3
// 331.533 us; speedup vs baseline: 8.4735x; 8.4735x over previous
//
#include <hip/hip_runtime.h>
#include <math.h>

#define B_   2
#define N_   2048
#define D_   1024
#define H_   16
#define HD_  64
#define BH_  32
#define M_   4096   // B_*N_

typedef __bf16 bf16x8 __attribute__((ext_vector_type(8)));
typedef float  f32x4  __attribute__((ext_vector_type(4)));

__device__ inline unsigned short f2b(float f) {
    unsigned u = __float_as_uint(f);
    u += 0x7FFFu + ((u >> 16) & 1u);
    return (unsigned short)(u >> 16);
}

// ---------------------------------------------------------------------------
// Convert x (4096x1024) and Wq/Wk/Wv/Wo (1024x1024 each) fp32 -> bf16 into one
// contiguous ws region: [x | wq | wk | wv | wo].
// ---------------------------------------------------------------------------
__global__ __launch_bounds__(256)
void cvt_all(const float* __restrict__ x,  const float* __restrict__ wq,
             const float* __restrict__ wk, const float* __restrict__ wv,
             const float* __restrict__ wo, ushort* __restrict__ dst)
{
    int i = blockIdx.x * 256 + threadIdx.x;      // float4 index
    if (i >= 2097152) return;                    // (4096*1024 + 4*1024*1024)/4
    int fi = i * 4;
    const float* s; int off;
    if (fi < 4194304) { s = x; off = fi; }
    else {
        int r = fi - 4194304;
        int wsel = r >> 20;                      // each W = 2^20 elements
        off = r & 1048575;
        s = (wsel == 0) ? wq : (wsel == 1) ? wk : (wsel == 2) ? wv : wo;
    }
    float4 f = *(const float4*)(s + off);
    ushort4 o;
    o.x = f2b(f.x); o.y = f2b(f.y); o.z = f2b(f.z); o.w = f2b(f.w);
    *(ushort4*)(dst + fi) = o;
}

// ---------------------------------------------------------------------------
// bf16 MFMA GEMM: C = A @ W^T. A [Mx1024] bf16 row-major, W [1024x1024] bf16
// row-major (both K-contiguous). 128x128 block tile, 4 waves in 2x2, each wave
// 64x64 (4x4 tiles of 16x16x32). BK=32.
// MODE 0: blockIdx.z selects W0/W1/W2 and O0/O1/O2; output bf16 scattered to
//         [BH][N][64]; z==0 (Q) scaled by 0.125.
// MODE 1: single W0; output fp32 [Mx1024] + bias.
// Layouts (HW-verified m89/m91/m120): A-frag lane=(m=lane&15,k=quad*8+j),
// B-frag lane=(k=quad*8+j,n=lane&15), C/D col=lane&15,row=quad*4+reg.
// ---------------------------------------------------------------------------
template <int MODE>
__global__ __launch_bounds__(256)
void gemm_mfma(const ushort* __restrict__ A,
               const ushort* __restrict__ W0, const ushort* __restrict__ W1,
               const ushort* __restrict__ W2, const float* __restrict__ bias,
               ushort* __restrict__ O0, ushort* __restrict__ O1,
               ushort* __restrict__ O2, float* __restrict__ Of)
{
    const int z = blockIdx.z;
    const ushort* W = (z == 0) ? W0 : (z == 1) ? W1 : W2;

    __shared__ alignas(16) ushort As[128][40];   // stride 40 -> 20 words: 2-way max
    __shared__ alignas(16) ushort Bs[128][40];

    const int t = threadIdx.x;
    const int lane = t & 63, w = t >> 6;
    const int quad = lane >> 4, l15 = lane & 15;
    const int wm = (w >> 1) * 64, wn = (w & 1) * 64;
    const int tileM = blockIdx.x * 128, tileN = blockIdx.y * 128;

    f32x4 acc[4][4];
#pragma unroll
    for (int mt = 0; mt < 4; ++mt)
#pragma unroll
        for (int nt = 0; nt < 4; ++nt) acc[mt][nt] = (f32x4){0.f, 0.f, 0.f, 0.f};

    for (int k0 = 0; k0 < D_; k0 += 32) {
        __syncthreads();
#pragma unroll
        for (int i = 0; i < 2; ++i) {
            int c = i * 256 + t;                 // 512 chunks of 8 bf16
            int row = c >> 2, kc = (c & 3) * 8;
            *(uint4*)&As[row][kc] = *(const uint4*)&A[(size_t)(tileM + row) * D_ + k0 + kc];
            *(uint4*)&Bs[row][kc] = *(const uint4*)&W[(size_t)(tileN + row) * D_ + k0 + kc];
        }
        __syncthreads();

        bf16x8 af[4], bf[4];
#pragma unroll
        for (int mt = 0; mt < 4; ++mt) af[mt] = *(const bf16x8*)&As[wm + mt * 16 + l15][quad * 8];
#pragma unroll
        for (int nt = 0; nt < 4; ++nt) bf[nt] = *(const bf16x8*)&Bs[wn + nt * 16 + l15][quad * 8];
#pragma unroll
        for (int mt = 0; mt < 4; ++mt)
#pragma unroll
            for (int nt = 0; nt < 4; ++nt)
                acc[mt][nt] = __builtin_amdgcn_mfma_f32_16x16x32_bf16(af[mt], bf[nt], acc[mt][nt], 0, 0, 0);
    }

    ushort* O = (z == 0) ? O0 : (z == 1) ? O1 : O2;
    const float scl = (MODE == 0 && z == 0) ? 0.125f : 1.0f;   // fold 1/sqrt(64) into Q
#pragma unroll
    for (int mt = 0; mt < 4; ++mt)
#pragma unroll
        for (int nt = 0; nt < 4; ++nt)
#pragma unroll
            for (int r = 0; r < 4; ++r) {
                int rg = tileM + wm + mt * 16 + quad * 4 + r;
                int cg = tileN + wn + nt * 16 + l15;
                float v = acc[mt][nt][r];
                if (MODE == 0) {
                    int b = rg >> 11, n = rg & (N_ - 1);
                    int h = cg >> 6, dd = cg & 63;
                    O[(((size_t)(b * H_ + h)) * N_ + n) * HD_ + dd] = f2b(v * scl);
                } else {
                    Of[(size_t)rg * D_ + cg] = v + bias[cg];
                }
            }
}

// ---------------------------------------------------------------------------
// MFMA adaptive-temperature causal flash attention.
// Grid (32 qt, 32 bh), 256 threads = 4 waves; wave w owns queries
// qt*64 + w*16 .. +15. Q/K/V bf16 [BH][N][64]; Q pre-scaled by 1/8.
// Shift-invariance: entropy H = log Z - S/Z and the beta-softmax are invariant
// under s -> s - C, so fixed C=8 replaces online max tracking entirely.
// Pass 1: Z=sum e^(s-C), S=sum (s-C)e^(s-C) -> H -> beta.
// Pass 2: w=e^(beta*(s-C)); O += w*V (MFMA, P via wave-private LDS roundtrip),
//         Z' += w; final O/Z'. Only diagonal key-block masks.
// ---------------------------------------------------------------------------
__global__ __launch_bounds__(256)
void attn_mfma(const ushort* __restrict__ Q, const ushort* __restrict__ K,
               const ushort* __restrict__ V, ushort* __restrict__ AO)
{
    const int qt = blockIdx.x;     // 64-query tile
    const int bh = blockIdx.y;
    const size_t kvbase = (size_t)bh * N_ * HD_;

    __shared__ alignas(16) ushort Ks[64][72];       // [key][hd]
    __shared__ alignas(16) ushort Vt[64][72];       // [hd][key] (transposed)
    __shared__ alignas(16) ushort Ps[4][16][72];    // wave-private P

    const int t = threadIdx.x;
    const int lane = t & 63, w = t >> 6;
    const int quad = lane >> 4, l15 = lane & 15;
    const float SH = 8.0f;

    // Q fragments (held in registers all kernel)
    bf16x8 aq[2];
    {
        const size_t qr = kvbase + (size_t)(qt * 64 + w * 16 + l15) * HD_;
        aq[0] = *(const bf16x8*)&Q[qr + quad * 8];
        aq[1] = *(const bf16x8*)&Q[qr + 32 + quad * 8];
    }

    float zAcc[4] = {0.f, 0.f, 0.f, 0.f};
    float sAcc[4] = {0.f, 0.f, 0.f, 0.f};

    // ---------------- pass 1: Z, S ----------------
    for (int kb = 0; kb <= qt; ++kb) {
        __syncthreads();
#pragma unroll
        for (int i = 0; i < 2; ++i) {
            int c = i * 256 + t;
            int key = c >> 3, kc = (c & 7) * 8;
            *(uint4*)&Ks[key][kc] = *(const uint4*)&K[kvbase + (size_t)(kb * 64 + key) * HD_ + kc];
        }
        __syncthreads();

        float ez[4] = {0.f, 0.f, 0.f, 0.f}, sz[4] = {0.f, 0.f, 0.f, 0.f};
#pragma unroll
        for (int nt = 0; nt < 4; ++nt) {
            f32x4 sv = (f32x4){0.f, 0.f, 0.f, 0.f};
            sv = __builtin_amdgcn_mfma_f32_16x16x32_bf16(aq[0], *(const bf16x8*)&Ks[nt * 16 + l15][quad * 8], sv, 0, 0, 0);
            sv = __builtin_amdgcn_mfma_f32_16x16x32_bf16(aq[1], *(const bf16x8*)&Ks[nt * 16 + l15][32 + quad * 8], sv, 0, 0, 0);
#pragma unroll
            for (int r = 0; r < 4; ++r) {
                bool ok = (kb < qt) || (nt * 16 + l15 <= w * 16 + quad * 4 + r);
                float sh = sv[r] - SH;
                float e = ok ? __expf(sh) : 0.f;
                ez[r] += e;
                sz[r] += e * sh;
            }
        }
#pragma unroll
        for (int r = 0; r < 4; ++r) {
            float a = ez[r], b = sz[r];
#pragma unroll
            for (int off = 1; off < 16; off <<= 1) {
                a += __shfl_xor(a, off);
                b += __shfl_xor(b, off);
            }
            zAcc[r] += a;
            sAcc[r] += b;
        }
    }

    // ---------------- entropy -> beta (per owned row) ----------------
    float beta[4];
#pragma unroll
    for (int r = 0; r < 4; ++r) {
        float Z = zAcc[r];
        float Hh = __logf(Z) - sAcc[r] / Z;
        float bb = 1.f;
        if (Hh > 0.5f) {
            float e2 = Hh * Hh;
            float p = -0.037f * e2 * e2 + 0.481f * e2 * Hh - 2.3f * e2 + 4.917f * Hh - 1.791f;
            bb = fmaxf(p, 1.f);
        }
        beta[r] = bb;
    }

    // ---------------- pass 2: O, Z' ----------------
    f32x4 ov[4];
#pragma unroll
    for (int nt = 0; nt < 4; ++nt) ov[nt] = (f32x4){0.f, 0.f, 0.f, 0.f};
    float zp[4] = {0.f, 0.f, 0.f, 0.f};

    for (int kb = 0; kb <= qt; ++kb) {
        __syncthreads();
#pragma unroll
        for (int i = 0; i < 2; ++i) {
            // K: coalesced read, row-contiguous LDS write
            int c = i * 256 + t;
            int key = c >> 3, kc = (c & 7) * 8;
            *(uint4*)&Ks[key][kc] = *(const uint4*)&K[kvbase + (size_t)(kb * 64 + key) * HD_ + kc];
            // V: strided read (L2-absorbed), conflict-free transposed LDS write.
            // c>>6 spans 0..7 across both i-iterations (c = i*256+t), so kcv
            // covers hd 0..56 in 8-chunks exactly once.  (R2 bug: had +i*32,
            // which ran Vt rows to 95 -> OOB into Ps + half of Vt left
            // uninitialized -> NaN from the PV MFMA.)
            int keyv = c & 63, kcv = (c >> 6) * 8;
            uint4 vv = *(const uint4*)&V[kvbase + (size_t)(kb * 64 + keyv) * HD_ + kcv];
            const ushort* pv = (const ushort*)&vv;
#pragma unroll
            for (int j = 0; j < 8; ++j) Vt[kcv + j][keyv] = pv[j];
        }
        __syncthreads();

        float wv[4][4];
#pragma unroll
        for (int nt = 0; nt < 4; ++nt) {
            f32x4 sv = (f32x4){0.f, 0.f, 0.f, 0.f};
            sv = __builtin_amdgcn_mfma_f32_16x16x32_bf16(aq[0], *(const bf16x8*)&Ks[nt * 16 + l15][quad * 8], sv, 0, 0, 0);
            sv = __builtin_amdgcn_mfma_f32_16x16x32_bf16(aq[1], *(const bf16x8*)&Ks[nt * 16 + l15][32 + quad * 8], sv, 0, 0, 0);
#pragma unroll
            for (int r = 0; r < 4; ++r) {
                bool ok = (kb < qt) || (nt * 16 + l15 <= w * 16 + quad * 4 + r);
                wv[nt][r] = ok ? __expf(beta[r] * (sv[r] - SH)) : 0.f;
            }
        }
        // P -> wave-private LDS (C-layout write, A-layout read; same wave, in-order DS)
#pragma unroll
        for (int nt = 0; nt < 4; ++nt)
#pragma unroll
            for (int r = 0; r < 4; ++r)
                Ps[w][quad * 4 + r][nt * 16 + l15] = f2b(wv[nt][r]);
        // Z' row sums
#pragma unroll
        for (int r = 0; r < 4; ++r) {
            float a = wv[0][r] + wv[1][r] + wv[2][r] + wv[3][r];
#pragma unroll
            for (int off = 1; off < 16; off <<= 1) a += __shfl_xor(a, off);
            zp[r] += a;
        }
        // P @ V
        bf16x8 pa0 = *(const bf16x8*)&Ps[w][l15][quad * 8];
        bf16x8 pa1 = *(const bf16x8*)&Ps[w][l15][32 + quad * 8];
#pragma unroll
        for (int nt = 0; nt < 4; ++nt) {
            ov[nt] = __builtin_amdgcn_mfma_f32_16x16x32_bf16(pa0, *(const bf16x8*)&Vt[nt * 16 + l15][quad * 8], ov[nt], 0, 0, 0);
            ov[nt] = __builtin_amdgcn_mfma_f32_16x16x32_bf16(pa1, *(const bf16x8*)&Vt[nt * 16 + l15][32 + quad * 8], ov[nt], 0, 0, 0);
        }
    }

    // ---------------- write AO [B, N, D] bf16 ----------------
    const int b = bh >> 4, h = bh & 15;
#pragma unroll
    for (int r = 0; r < 4; ++r) {
        int qg = qt * 64 + w * 16 + quad * 4 + r;
        float inv = 1.f / zp[r];
        size_t rowoff = ((size_t)(b * N_ + qg)) * D_ + h * HD_;
#pragma unroll
        for (int nt = 0; nt < 4; ++nt)
            AO[rowoff + nt * 16 + l15] = f2b(ov[nt][r] * inv);
    }
}

// ---------------------------------------------------------------------------
extern "C" void kernel_launch(void* const* d_in, const int* in_sizes, int n_in,
                              void* d_out, int out_size, void* d_ws, size_t ws_size,
                              hipStream_t stream)
{
    const float* x  = (const float*)d_in[0];
    const float* Wq = (const float*)d_in[1];
    const float* Wk = (const float*)d_in[2];
    const float* Wv = (const float*)d_in[3];
    const float* Wo = (const float*)d_in[4];
    const float* bo = (const float*)d_in[5];
    float* out = (float*)d_out;

    ushort* ws  = (ushort*)d_ws;
    ushort* xb  = ws;                       // 4096*1024
    ushort* wqb = ws + 4194304;             // 1024*1024 each
    ushort* wkb = ws + 5242880;
    ushort* wvb = ws + 6291456;
    ushort* wob = ws + 7340032;
    ushort* Qb  = ws + 8388608;             // [32][2048][64] each
    ushort* Kb  = ws + 12582912;
    ushort* Vb  = ws + 16777216;
    ushort* aob = ws + 20971520;            // 4096*1024

    cvt_all<<<8192, 256, 0, stream>>>(x, Wq, Wk, Wv, Wo, xb);

    gemm_mfma<0><<<dim3(32, 8, 3), 256, 0, stream>>>(
        xb, wqb, wkb, wvb, nullptr, Qb, Kb, Vb, nullptr);

    attn_mfma<<<dim3(32, 32), 256, 0, stream>>>(Qb, Kb, Vb, aob);

    gemm_mfma<1><<<dim3(32, 8, 1), 256, 0, stream>>>(
        aob, wob, nullptr, nullptr, bo, nullptr, nullptr, nullptr, out);
}

// Round 4
// 254.821 us; speedup vs baseline: 11.0244x; 1.3010x over previous
//
#include <hip/hip_runtime.h>
#include <math.h>

#define B_   2
#define N_   2048
#define D_   1024
#define H_   16
#define HD_  64
#define BH_  32
#define M_   4096   // B_*N_

typedef __bf16 bf16x8 __attribute__((ext_vector_type(8)));
typedef float  f32x4  __attribute__((ext_vector_type(4)));
typedef __attribute__((address_space(3))) uint  lds_u32;
typedef __attribute__((address_space(1))) uint  glob_u32;

__device__ inline unsigned short f2b(float f) {
    unsigned u = __float_as_uint(f);
    u += 0x7FFFu + ((u >> 16) & 1u);
    return (unsigned short)(u >> 16);
}

// ---------------------------------------------------------------------------
// Convert x (4096x1024) and Wq/Wk/Wv/Wo (1024x1024 each) fp32 -> bf16 into one
// contiguous ws region: [x | wq | wk | wv | wo].
// ---------------------------------------------------------------------------
__global__ __launch_bounds__(256)
void cvt_all(const float* __restrict__ x,  const float* __restrict__ wq,
             const float* __restrict__ wk, const float* __restrict__ wv,
             const float* __restrict__ wo, ushort* __restrict__ dst)
{
    int i = blockIdx.x * 256 + threadIdx.x;      // float4 index
    if (i >= 2097152) return;                    // (4096*1024 + 4*1024*1024)/4
    int fi = i * 4;
    const float* s; int off;
    if (fi < 4194304) { s = x; off = fi; }
    else {
        int r = fi - 4194304;
        int wsel = r >> 20;                      // each W = 2^20 elements
        off = r & 1048575;
        s = (wsel == 0) ? wq : (wsel == 1) ? wk : (wsel == 2) ? wv : wo;
    }
    float4 f = *(const float4*)(s + off);
    ushort4 o;
    o.x = f2b(f.x); o.y = f2b(f.y); o.z = f2b(f.z); o.w = f2b(f.w);
    *(ushort4*)(dst + fi) = o;
}

// ---------------------------------------------------------------------------
// bf16 MFMA GEMM: C = A @ W^T. A [Mx1024] bf16 row-major, W [1024x1024] bf16
// row-major. 128x128 tile, 4 waves 2x2, 64x64/wave, BK=32.
// Staging via global_load_lds width=16 (m97 pattern): LDS unpadded [128][32]
// (frag-read bank pattern desk-checked: 8 words/bank = the 8-cycle minimum;
// lane-order deposit forbids padding).
// MODE 0: z selects Wq/Wk/Wv. z=0 (Q) scaled 0.125, scatter [BH][N][64];
//         z=1 (K) scatter [BH][N][64]; z=2 (V) written TRANSPOSED
//         [BH][HD][N] (ushort4 per (mt,nt): r-consecutive rows = n-consecutive).
// MODE 1: fp32 [Mx1024] + bias.
// Layouts (HW-verified m89/m91/m120): A-frag (m=lane&15, k=quad*8+j),
// B-frag (k=quad*8+j, n=lane&15), C/D col=lane&15, row=quad*4+reg.
// ---------------------------------------------------------------------------
template <int MODE>
__global__ __launch_bounds__(256)
void gemm_mfma(const ushort* __restrict__ A,
               const ushort* __restrict__ W0, const ushort* __restrict__ W1,
               const ushort* __restrict__ W2, const float* __restrict__ bias,
               ushort* __restrict__ O0, ushort* __restrict__ O1,
               ushort* __restrict__ O2, float* __restrict__ Of)
{
    const int z = blockIdx.z;
    const ushort* W = (z == 0) ? W0 : (z == 1) ? W1 : W2;

    __shared__ alignas(16) ushort As[128][32];
    __shared__ alignas(16) ushort Bs[128][32];

    const int t = threadIdx.x;
    const int lane = t & 63, w = t >> 6;
    const int quad = lane >> 4, l15 = lane & 15;
    const int wm = (w >> 1) * 64, wn = (w & 1) * 64;
    const int tileM = blockIdx.x * 128, tileN = blockIdx.y * 128;
    const int crow = lane >> 2;          // chunk row 0..15
    const int ccol = (lane & 3) * 8;     // ushort col offset

    f32x4 acc[4][4];
#pragma unroll
    for (int mt = 0; mt < 4; ++mt)
#pragma unroll
        for (int nt = 0; nt < 4; ++nt) acc[mt][nt] = (f32x4){0.f, 0.f, 0.f, 0.f};

    for (int k0 = 0; k0 < D_; k0 += 32) {
        __syncthreads();
        // wave w stages A chunks {2w,2w+1} and B chunks {2w,2w+1}; each
        // global_load_lds moves 64 lanes x 16B = 16 rows of 64B.
#pragma unroll
        for (int cc = 0; cc < 2; ++cc) {
            int ch = w * 2 + cc;
            const ushort* ga = &A[(size_t)(tileM + ch * 16 + crow) * D_ + k0 + ccol];
            __builtin_amdgcn_global_load_lds((const glob_u32*)ga, (lds_u32*)&As[ch * 16][0], 16, 0, 0);
            const ushort* gb = &W[(size_t)(tileN + ch * 16 + crow) * D_ + k0 + ccol];
            __builtin_amdgcn_global_load_lds((const glob_u32*)gb, (lds_u32*)&Bs[ch * 16][0], 16, 0, 0);
        }
        __syncthreads();

        bf16x8 af[4], bf[4];
#pragma unroll
        for (int mt = 0; mt < 4; ++mt) af[mt] = *(const bf16x8*)&As[wm + mt * 16 + l15][quad * 8];
#pragma unroll
        for (int nt = 0; nt < 4; ++nt) bf[nt] = *(const bf16x8*)&Bs[wn + nt * 16 + l15][quad * 8];
#pragma unroll
        for (int mt = 0; mt < 4; ++mt)
#pragma unroll
            for (int nt = 0; nt < 4; ++nt)
                acc[mt][nt] = __builtin_amdgcn_mfma_f32_16x16x32_bf16(af[mt], bf[nt], acc[mt][nt], 0, 0, 0);
    }

    ushort* O = (z == 0) ? O0 : (z == 1) ? O1 : O2;
    const float scl = (MODE == 0 && z == 0) ? 0.125f : 1.0f;
#pragma unroll
    for (int mt = 0; mt < 4; ++mt)
#pragma unroll
        for (int nt = 0; nt < 4; ++nt) {
            if (MODE == 0 && z == 2) {
                // V transposed: Vt[bh][dd][n], 4 consecutive n per 8B store
                int rg0 = tileM + wm + mt * 16 + quad * 4;
                int cg  = tileN + wn + nt * 16 + l15;
                int b = rg0 >> 11, n0 = rg0 & (N_ - 1);
                int h = cg >> 6, dd = cg & 63;
                ushort4 o4;
                o4.x = f2b(acc[mt][nt][0]); o4.y = f2b(acc[mt][nt][1]);
                o4.z = f2b(acc[mt][nt][2]); o4.w = f2b(acc[mt][nt][3]);
                *(ushort4*)&O[((size_t)((b * H_ + h) * HD_ + dd)) * N_ + n0] = o4;
            } else {
#pragma unroll
                for (int r = 0; r < 4; ++r) {
                    int rg = tileM + wm + mt * 16 + quad * 4 + r;
                    int cg = tileN + wn + nt * 16 + l15;
                    float v = acc[mt][nt][r];
                    if (MODE == 0) {
                        int b = rg >> 11, n = rg & (N_ - 1);
                        int h = cg >> 6, dd = cg & 63;
                        O[(((size_t)(b * H_ + h)) * N_ + n) * HD_ + dd] = f2b(v * scl);
                    } else {
                        Of[(size_t)rg * D_ + cg] = v + bias[cg];
                    }
                }
            }
        }
}

// ---------------------------------------------------------------------------
// MFMA adaptive-temperature causal flash attention.
// 1D grid, 1024 blocks, LPT order: qt = 31 - bid/32 (longest blocks first ->
// balanced dynamic packing), bh = bid&31 (XCD ~ bh%8 -> K/V L2 locality).
// 4 waves; wave w owns queries qt*64 + w*16 .. +15.
// Q/K bf16 [BH][N][64]; V pre-transposed [BH][64][N]; Q pre-scaled 1/8.
// Fixed shift C=8 (entropy & beta-softmax shift-invariant; |s|<~8).
// Pass 1: Z=sum e^(s-C), S=sum (s-C)e^(s-C) -> H=logZ-S/Z -> beta.
// Pass 2: w=e^(beta*(s-C)); O += w*V (P via wave-private LDS), Z' += w; O/Z'.
// ---------------------------------------------------------------------------
__global__ __launch_bounds__(256)
void attn_mfma(const ushort* __restrict__ Q, const ushort* __restrict__ K,
               const ushort* __restrict__ VT, ushort* __restrict__ AO)
{
    const int bid = blockIdx.x;
    const int qt = 31 - (bid >> 5);
    const int bh = bid & 31;
    const size_t kvbase = (size_t)bh * N_ * HD_;

    __shared__ alignas(16) ushort Ks[64][72];       // [key][hd]
    __shared__ alignas(16) ushort Vt[64][72];       // [hd][key]
    __shared__ alignas(16) ushort Ps[4][16][72];    // wave-private P (64 keys/row)

    const int t = threadIdx.x;
    const int lane = t & 63, w = t >> 6;
    const int quad = lane >> 4, l15 = lane & 15;
    const float SH = 8.0f;

    bf16x8 aq[2];
    {
        const size_t qr = kvbase + (size_t)(qt * 64 + w * 16 + l15) * HD_;
        aq[0] = *(const bf16x8*)&Q[qr + quad * 8];
        aq[1] = *(const bf16x8*)&Q[qr + 32 + quad * 8];
    }

    float zAcc[4] = {0.f, 0.f, 0.f, 0.f};
    float sAcc[4] = {0.f, 0.f, 0.f, 0.f};

    // ---------------- pass 1: Z, S ----------------
    for (int kb = 0; kb <= qt; ++kb) {
        __syncthreads();
#pragma unroll
        for (int i = 0; i < 2; ++i) {
            int c = i * 256 + t;
            int key = c >> 3, kc = (c & 7) * 8;
            *(uint4*)&Ks[key][kc] = *(const uint4*)&K[kvbase + (size_t)(kb * 64 + key) * HD_ + kc];
        }
        __syncthreads();

        float ez[4] = {0.f, 0.f, 0.f, 0.f}, sz[4] = {0.f, 0.f, 0.f, 0.f};
#pragma unroll
        for (int nt = 0; nt < 4; ++nt) {
            f32x4 sv = (f32x4){0.f, 0.f, 0.f, 0.f};
            sv = __builtin_amdgcn_mfma_f32_16x16x32_bf16(aq[0], *(const bf16x8*)&Ks[nt * 16 + l15][quad * 8], sv, 0, 0, 0);
            sv = __builtin_amdgcn_mfma_f32_16x16x32_bf16(aq[1], *(const bf16x8*)&Ks[nt * 16 + l15][32 + quad * 8], sv, 0, 0, 0);
#pragma unroll
            for (int r = 0; r < 4; ++r) {
                bool ok = (kb < qt) || (nt * 16 + l15 <= w * 16 + quad * 4 + r);
                float sh = sv[r] - SH;
                float e = ok ? __expf(sh) : 0.f;
                ez[r] += e;
                sz[r] += e * sh;
            }
        }
#pragma unroll
        for (int r = 0; r < 4; ++r) {
            float a = ez[r], b = sz[r];
#pragma unroll
            for (int off = 1; off < 16; off <<= 1) {
                a += __shfl_xor(a, off);
                b += __shfl_xor(b, off);
            }
            zAcc[r] += a;
            sAcc[r] += b;
        }
    }

    // ---------------- entropy -> beta ----------------
    float beta[4];
#pragma unroll
    for (int r = 0; r < 4; ++r) {
        float Z = zAcc[r];
        float Hh = __logf(Z) - sAcc[r] / Z;
        float bb = 1.f;
        if (Hh > 0.5f) {
            float e2 = Hh * Hh;
            float p = -0.037f * e2 * e2 + 0.481f * e2 * Hh - 2.3f * e2 + 4.917f * Hh - 1.791f;
            bb = fmaxf(p, 1.f);
        }
        beta[r] = bb;
    }

    // ---------------- pass 2: O, Z' ----------------
    f32x4 ov[4];
#pragma unroll
    for (int nt = 0; nt < 4; ++nt) ov[nt] = (f32x4){0.f, 0.f, 0.f, 0.f};
    float zp[4] = {0.f, 0.f, 0.f, 0.f};

    for (int kb = 0; kb <= qt; ++kb) {
        __syncthreads();
#pragma unroll
        for (int i = 0; i < 2; ++i) {
            int c = i * 256 + t;
            int key = c >> 3, kc = (c & 7) * 8;   // doubles as (hd, key-chunk) for Vt
            *(uint4*)&Ks[key][kc] = *(const uint4*)&K[kvbase + (size_t)(kb * 64 + key) * HD_ + kc];
            // VT[bh][hd][n]: rows are hd -> vectorized stage, no scalar transpose
            *(uint4*)&Vt[key][kc] = *(const uint4*)&VT[kvbase + (size_t)key * N_ + kb * 64 + kc];
        }
        __syncthreads();

        float wv[4][4];
#pragma unroll
        for (int nt = 0; nt < 4; ++nt) {
            f32x4 sv = (f32x4){0.f, 0.f, 0.f, 0.f};
            sv = __builtin_amdgcn_mfma_f32_16x16x32_bf16(aq[0], *(const bf16x8*)&Ks[nt * 16 + l15][quad * 8], sv, 0, 0, 0);
            sv = __builtin_amdgcn_mfma_f32_16x16x32_bf16(aq[1], *(const bf16x8*)&Ks[nt * 16 + l15][32 + quad * 8], sv, 0, 0, 0);
#pragma unroll
            for (int r = 0; r < 4; ++r) {
                bool ok = (kb < qt) || (nt * 16 + l15 <= w * 16 + quad * 4 + r);
                wv[nt][r] = ok ? __expf(beta[r] * (sv[r] - SH)) : 0.f;
            }
        }
        // P -> wave-private LDS (C-layout write, A-layout read; same-wave DS in-order)
#pragma unroll
        for (int nt = 0; nt < 4; ++nt)
#pragma unroll
            for (int r = 0; r < 4; ++r)
                Ps[w][quad * 4 + r][nt * 16 + l15] = f2b(wv[nt][r]);
#pragma unroll
        for (int r = 0; r < 4; ++r) {
            float a = wv[0][r] + wv[1][r] + wv[2][r] + wv[3][r];
#pragma unroll
            for (int off = 1; off < 16; off <<= 1) a += __shfl_xor(a, off);
            zp[r] += a;
        }
        bf16x8 pa0 = *(const bf16x8*)&Ps[w][l15][quad * 8];
        bf16x8 pa1 = *(const bf16x8*)&Ps[w][l15][32 + quad * 8];
#pragma unroll
        for (int nt = 0; nt < 4; ++nt) {
            ov[nt] = __builtin_amdgcn_mfma_f32_16x16x32_bf16(pa0, *(const bf16x8*)&Vt[nt * 16 + l15][quad * 8], ov[nt], 0, 0, 0);
            ov[nt] = __builtin_amdgcn_mfma_f32_16x16x32_bf16(pa1, *(const bf16x8*)&Vt[nt * 16 + l15][32 + quad * 8], ov[nt], 0, 0, 0);
        }
    }

    const int b = bh >> 4, h = bh & 15;
#pragma unroll
    for (int r = 0; r < 4; ++r) {
        int qg = qt * 64 + w * 16 + quad * 4 + r;
        float inv = 1.f / zp[r];
        size_t rowoff = ((size_t)(b * N_ + qg)) * D_ + h * HD_;
#pragma unroll
        for (int nt = 0; nt < 4; ++nt)
            AO[rowoff + nt * 16 + l15] = f2b(ov[nt][r] * inv);
    }
}

// ---------------------------------------------------------------------------
extern "C" void kernel_launch(void* const* d_in, const int* in_sizes, int n_in,
                              void* d_out, int out_size, void* d_ws, size_t ws_size,
                              hipStream_t stream)
{
    const float* x  = (const float*)d_in[0];
    const float* Wq = (const float*)d_in[1];
    const float* Wk = (const float*)d_in[2];
    const float* Wv = (const float*)d_in[3];
    const float* Wo = (const float*)d_in[4];
    const float* bo = (const float*)d_in[5];
    float* out = (float*)d_out;

    ushort* ws  = (ushort*)d_ws;
    ushort* xb  = ws;                       // 4096*1024
    ushort* wqb = ws + 4194304;
    ushort* wkb = ws + 5242880;
    ushort* wvb = ws + 6291456;
    ushort* wob = ws + 7340032;
    ushort* Qb  = ws + 8388608;             // [32][2048][64]
    ushort* Kb  = ws + 12582912;            // [32][2048][64]
    ushort* Vtb = ws + 16777216;            // [32][64][2048]  (transposed V)
    ushort* aob = ws + 20971520;            // 4096*1024

    cvt_all<<<8192, 256, 0, stream>>>(x, Wq, Wk, Wv, Wo, xb);

    gemm_mfma<0><<<dim3(32, 8, 3), 256, 0, stream>>>(
        xb, wqb, wkb, wvb, nullptr, Qb, Kb, Vtb, nullptr);

    attn_mfma<<<dim3(1024), 256, 0, stream>>>(Qb, Kb, Vtb, aob);

    gemm_mfma<1><<<dim3(32, 8, 1), 256, 0, stream>>>(
        aob, wob, nullptr, nullptr, bo, nullptr, nullptr, nullptr, out);
}